// Round 1
// baseline (323.045 us; speedup 1.0000x reference)
//
#include <hip/hip_runtime.h>

// Inverse-scatter map: slot[t] = j+1 if scatter_idx[j] == t (valid), else 0.
__global__ void build_slot_kernel(const int* __restrict__ scatter_idx,
                                  int* __restrict__ slot, int n, int T) {
    int j = blockIdx.x * blockDim.x + threadIdx.x;
    if (j < n) {
        int t = scatter_idx[j];
        if ((unsigned)t < (unsigned)T) slot[t] = j + 1;
    }
}

// One token per blockIdx.y; float4-vectorized row copy with scale.
// Branch on slot[t] is uniform within a block -> no divergence.
__global__ void moe_out_kernel(const float4* __restrict__ eo,
                               const float4* __restrict__ x,
                               const float* __restrict__ rpm,
                               const int* __restrict__ slot,
                               float4* __restrict__ out, int D4) {
    int t = blockIdx.y;
    int c = blockIdx.x * blockDim.x + threadIdx.x;
    if (c >= D4) return;
    int s = slot[t];
    const float4* src;
    float f;
    if (s > 0) {
        src = eo + (size_t)(s - 1) * D4 + c;
        f = rpm[t];
    } else {
        src = x + (size_t)t * D4 + c;
        f = 1.0f;
    }
    float4 v = *src;
    v.x *= f; v.y *= f; v.z *= f; v.w *= f;
    out[(size_t)t * D4 + c] = v;
}

extern "C" void kernel_launch(void* const* d_in, const int* in_sizes, int n_in,
                              void* d_out, int out_size, void* d_ws, size_t ws_size,
                              hipStream_t stream) {
    const float* eo          = (const float*)d_in[0];  // (E*C, D) fp32
    const float* x           = (const float*)d_in[1];  // (B, S, D) fp32
    const float* rpm         = (const float*)d_in[2];  // (T,) fp32
    const int*   scatter_idx = (const int*)d_in[3];    // (E*C,) int32
    // d_in[4] (dropped_mask) intentionally unused: dropped == not-in-scatter_idx.

    const int T  = in_sizes[2];            // 16384 tokens
    const int D  = in_sizes[1] / T;        // 2048
    const int n  = in_sizes[3];            // E*C = 20480 slots
    const int D4 = D / 4;                  // 512 float4 per row

    int* slot = (int*)d_ws;                // T ints of scratch (ws re-poisoned each call)
    hipMemsetAsync(slot, 0, (size_t)T * sizeof(int), stream);

    build_slot_kernel<<<(n + 255) / 256, 256, 0, stream>>>(scatter_idx, slot, n, T);

    dim3 grid((D4 + 255) / 256, T);        // (2, 16384)
    moe_out_kernel<<<grid, 256, 0, stream>>>(
        (const float4*)eo, (const float4*)x, rpm, slot, (float4*)d_out, D4);
}